// Round 1
// baseline (1413.923 us; speedup 1.0000x reference)
//
#include <hip/hip_runtime.h>

#define ALPHA 0.01f

__device__ __forceinline__ void atomAddF(float* p, float v) {
  unsafeAtomicAdd(p, v);  // native global_atomic_add_f32 on gfx950
}

// ---------------- input linear + relu: H[N,128] = relu(X[N,128] @ W[128,128]^T + b) ----
// W staged in LDS (64KB), XOR-swizzled so strided-column reads are bank-conflict-free.
// Block 256 threads -> 64 rows x 128 cols tile; per-thread 8 rows x 4 cols.
__global__ __launch_bounds__(256) void lin_relu_kernel(
    const float* __restrict__ X, const float* __restrict__ W,
    const float* __restrict__ B, float* __restrict__ H, int N)
{
  __shared__ float Ws[128 * 128];
  const int t = threadIdx.x;
#pragma unroll
  for (int j = 0; j < 64; ++j) {             // 16384 elems / 256 threads
    int idx = t + 256 * j;
    int c = idx >> 7, k = idx & 127;
    Ws[(c << 7) | (k ^ (c & 31))] = W[idx];  // swizzled store
  }
  __syncthreads();

  const int lane  = t & 31;
  const int rbase = blockIdx.x * 64 + ((t >> 5) << 3);

  float acc[8][4];
#pragma unroll
  for (int i = 0; i < 8; ++i)
#pragma unroll
    for (int m = 0; m < 4; ++m) acc[i][m] = 0.f;

  for (int k4 = 0; k4 < 32; ++k4) {
    float4 xv[8];
#pragma unroll
    for (int i = 0; i < 8; ++i) {
      int r = rbase + i;
      xv[i] = (r < N) ? *(const float4*)(X + (size_t)r * 128 + k4 * 4)
                      : make_float4(0.f, 0.f, 0.f, 0.f);
    }
#pragma unroll
    for (int kk = 0; kk < 4; ++kk) {
      int k = k4 * 4 + kk;
      int ks = k ^ lane;                      // swizzled k (c&31 == lane for all 4 cols)
      float wv0 = Ws[((lane      ) << 7) | ks];
      float wv1 = Ws[((lane +  32) << 7) | ks];
      float wv2 = Ws[((lane +  64) << 7) | ks];
      float wv3 = Ws[((lane +  96) << 7) | ks];
#pragma unroll
      for (int i = 0; i < 8; ++i) {
        float xk = (kk == 0) ? xv[i].x : (kk == 1) ? xv[i].y : (kk == 2) ? xv[i].z : xv[i].w;
        acc[i][0] += xk * wv0;
        acc[i][1] += xk * wv1;
        acc[i][2] += xk * wv2;
        acc[i][3] += xk * wv3;
      }
    }
  }

#pragma unroll
  for (int m = 0; m < 4; ++m) {
    int c = lane + 32 * m;
    float b = B[c];
#pragma unroll
    for (int i = 0; i < 8; ++i) {
      int r = rbase + i;
      if (r < N) {
        float v = acc[i][m] + b;
        H[(size_t)r * 128 + c] = v > 0.f ? v : 0.f;
      }
    }
  }
}

// ---------------- projection: G[N,16] = H[N,128] @ Wo[16,128]^T (no bias) -------------
__global__ __launch_bounds__(256) void proj_kernel(
    const float* __restrict__ H, const float* __restrict__ Wo,
    float* __restrict__ G, int N)
{
  int t = threadIdx.x;
  int row = blockIdx.x * 16 + (t >> 4);
  int o = t & 15;
  if (row >= N) return;
  const float4* hr = (const float4*)(H + (size_t)row * 128);
  const float4* wr = (const float4*)(Wo + o * 128);
  float acc = 0.f;
#pragma unroll 8
  for (int k = 0; k < 32; ++k) {
    float4 a = hr[k], b = wr[k];
    acc += a.x * b.x + a.y * b.y + a.z * b.z + a.w * b.w;
  }
  G[(size_t)row * 16 + o] = acc;
}

// ---------------- degree count (float, exact for counts < 2^24) ----------------------
__global__ void deg_count_kernel(const int* __restrict__ dst, float* __restrict__ deg, int E)
{
  int i = blockIdx.x * 256 + threadIdx.x;
  if (i < E) atomAddF(&deg[dst[i]], 1.0f);
}

// ---------------- 16-dim scatter-mean: T[dst] += G[src] / deg[dst] -------------------
// 4 lanes per edge (float4 each). 64 edges per block.
__global__ __launch_bounds__(256) void scatter16_kernel(
    const float* __restrict__ G, float* __restrict__ T,
    const int* __restrict__ src, const int* __restrict__ dst,
    const float* __restrict__ deg, int E)
{
  int e = blockIdx.x * 64 + (threadIdx.x >> 2);
  if (e >= E) return;
  int l4 = (threadIdx.x & 3) * 4;
  int s = src[e], d = dst[e];
  float scale = 1.0f / fmaxf(deg[d], 1.0f);
  float4 v = *(const float4*)(G + (size_t)s * 16 + l4);
  float* p = T + (size_t)d * 16 + l4;
  atomAddF(p + 0, v.x * scale);
  atomAddF(p + 1, v.y * scale);
  atomAddF(p + 2, v.z * scale);
  atomAddF(p + 3, v.w * scale);
}

// ---------------- dual scatter into out: out[dst] += (a*G[src] + c*T[src]) / deg[dst] --
__global__ __launch_bounds__(256) void scatter16_dual_kernel(
    const float* __restrict__ G, const float* __restrict__ T,
    float* __restrict__ out,
    const int* __restrict__ src, const int* __restrict__ dst,
    const float* __restrict__ deg, float a, float c, int E)
{
  int e = blockIdx.x * 64 + (threadIdx.x >> 2);
  if (e >= E) return;
  int l4 = (threadIdx.x & 3) * 4;
  int s = src[e], d = dst[e];
  float scale = 1.0f / fmaxf(deg[d], 1.0f);
  float4 g = *(const float4*)(G + (size_t)s * 16 + l4);
  float4 tt = *(const float4*)(T + (size_t)s * 16 + l4);
  float* p = out + (size_t)d * 16 + l4;
  atomAddF(p + 0, (a * g.x + c * tt.x) * scale);
  atomAddF(p + 1, (a * g.y + c * tt.y) * scale);
  atomAddF(p + 2, (a * g.z + c * tt.z) * scale);
  atomAddF(p + 3, (a * g.w + c * tt.w) * scale);
}

// ---------------- out init: out = alpha^2 * g_m + b_out ------------------------------
__global__ void init_out_kernel(const float* __restrict__ Gm, const float* __restrict__ bo,
                                float* __restrict__ out, int n)
{
  int i = blockIdx.x * 256 + threadIdx.x;
  if (i < n) out[i] = ALPHA * ALPHA * Gm[i] + bo[i & 15];
}

extern "C" void kernel_launch(void* const* d_in, const int* in_sizes, int n_in,
                              void* d_out, int out_size, void* d_ws, size_t ws_size,
                              hipStream_t stream)
{
  const float* x_user  = (const float*)d_in[0];
  const float* x_movie = (const float*)d_in[1];
  const float* x_dir   = (const float*)d_in[2];
  const int* rates_src = (const int*)d_in[3];
  const int* rates_dst = (const int*)d_in[4];
  const int* rby_src   = (const int*)d_in[5];
  const int* rby_dst   = (const int*)d_in[6];
  const int* dir_src   = (const int*)d_in[7];
  const int* dir_dst   = (const int*)d_in[8];
  const int* dby_src   = (const int*)d_in[9];
  const int* dby_dst   = (const int*)d_in[10];
  const float* W_user  = (const float*)d_in[11];
  const float* b_user  = (const float*)d_in[12];
  const float* W_movie = (const float*)d_in[13];
  const float* b_movie = (const float*)d_in[14];
  const float* W_dir   = (const float*)d_in[15];
  const float* b_dir   = (const float*)d_in[16];
  const float* W_out   = (const float*)d_in[17];
  const float* b_out   = (const float*)d_in[18];

  const int NU = in_sizes[0] / 128, NM = in_sizes[1] / 128, ND = in_sizes[2] / 128;
  const int Er = in_sizes[3], Erby = in_sizes[5], Edir = in_sizes[7], Edby = in_sizes[9];

  // ---- workspace layout
  char* w = (char*)d_ws;
  size_t off = 0;
  auto take = [&](size_t bytes) { char* p = w + off; off += (bytes + 255) & ~(size_t)255; return p; };
  float* h_u = (float*)take((size_t)NU * 128 * 4);
  float* h_m = (float*)take((size_t)NM * 128 * 4);
  float* h_d = (float*)take((size_t)ND * 128 * 4);
  float* g_u = (float*)take((size_t)NU * 16 * 4);
  float* g_m = (float*)take((size_t)NM * 16 * 4);
  float* g_d = (float*)take((size_t)ND * 16 * 4);
  // zero region start: t_u, t_d, 4 degree arrays (contiguous)
  size_t zero_begin = off;
  float* t_u     = (float*)take((size_t)NU * 16 * 4);
  float* t_d     = (float*)take((size_t)ND * 16 * 4);
  float* deg_r   = (float*)take((size_t)NM * 4);
  float* deg_dir = (float*)take((size_t)NM * 4);
  float* deg_rby = (float*)take((size_t)NU * 4);
  float* deg_dby = (float*)take((size_t)ND * 4);
  size_t zero_bytes = off - zero_begin;
  if (off > ws_size) return;  // workspace too small; nothing sane to do

  // 1. zero accumulators + degree arrays
  hipMemsetAsync(w + zero_begin, 0, zero_bytes, stream);

  // 2. degree counts
  deg_count_kernel<<<(Er   + 255) / 256, 256, 0, stream>>>(rates_dst, deg_r,   Er);
  deg_count_kernel<<<(Edir + 255) / 256, 256, 0, stream>>>(dir_dst,   deg_dir, Edir);
  deg_count_kernel<<<(Erby + 255) / 256, 256, 0, stream>>>(rby_dst,   deg_rby, Erby);
  deg_count_kernel<<<(Edby + 255) / 256, 256, 0, stream>>>(dby_dst,   deg_dby, Edby);

  // 3. input linear + relu
  lin_relu_kernel<<<(NU + 63) / 64, 256, 0, stream>>>(x_user,  W_user,  b_user,  h_u, NU);
  lin_relu_kernel<<<(NM + 63) / 64, 256, 0, stream>>>(x_movie, W_movie, b_movie, h_m, NM);
  lin_relu_kernel<<<(ND + 63) / 64, 256, 0, stream>>>(x_dir,   W_dir,   b_dir,   h_d, ND);

  // 4. project to 16-dim output space (linearity: mean commutes with @Wout^T)
  proj_kernel<<<(NU + 15) / 16, 256, 0, stream>>>(h_u, W_out, g_u, NU);
  proj_kernel<<<(NM + 15) / 16, 256, 0, stream>>>(h_m, W_out, g_m, NM);
  proj_kernel<<<(ND + 15) / 16, 256, 0, stream>>>(h_d, W_out, g_d, ND);

  // 5. t_u = mean_rby(g_m) [user], t_d = mean_dby(g_m) [director]
  scatter16_kernel<<<(Erby + 63) / 64, 256, 0, stream>>>(g_m, t_u, rby_src, rby_dst, deg_rby, Erby);
  scatter16_kernel<<<(Edby + 63) / 64, 256, 0, stream>>>(g_m, t_d, dby_src, dby_dst, deg_dby, Edby);

  // 6. out = alpha^2 * g_m + b_out
  init_out_kernel<<<(NM * 16 + 255) / 256, 256, 0, stream>>>(g_m, b_out, (float*)d_out, NM * 16);

  // 7. out += mean_rates(alpha*g_u + 0.5*t_u) + mean_dir(alpha*g_d + 0.5*t_d)
  scatter16_dual_kernel<<<(Er + 63) / 64, 256, 0, stream>>>(
      g_u, t_u, (float*)d_out, rates_src, rates_dst, deg_r, ALPHA, 0.5f, Er);
  scatter16_dual_kernel<<<(Edir + 63) / 64, 256, 0, stream>>>(
      g_d, t_d, (float*)d_out, dir_src, dir_dst, deg_dir, ALPHA, 0.5f, Edir);
}

// Round 2
// 1242.525 us; speedup vs baseline: 1.1379x; 1.1379x over previous
//
#include <hip/hip_runtime.h>

#define ALPHA 0.01f

__device__ __forceinline__ void atomAddF(float* p, float v) {
  unsafeAtomicAdd(p, v);  // native global_atomic_add_f32 on gfx950
}

// ---------------- fused input linear + relu + 16-dim projection ----------------------
// G[N,16] = relu(X[N,128] @ W[128,128]^T + b) @ Wo[16,128]^T
// One row per thread. x resident in VGPRs. W/b/Wo are wave-uniform -> s_load (SGPR),
// no LDS. 4 output channels c per iteration, 2 partial sums each = 8 indep FMA chains.
__global__ __launch_bounds__(256) void fused_lin_proj_kernel(
    const float* __restrict__ X, const float* __restrict__ W,
    const float* __restrict__ B, const float* __restrict__ Wo,
    float* __restrict__ G, int N)
{
  const int r = blockIdx.x * 256 + threadIdx.x;
  if (r >= N) return;

  float4 x[32];
  const float4* xr = (const float4*)(X + (size_t)r * 128);
#pragma unroll
  for (int i = 0; i < 32; ++i) x[i] = xr[i];

  float g[16];
#pragma unroll
  for (int o = 0; o < 16; ++o) g[o] = 0.f;

  for (int c0 = 0; c0 < 128; c0 += 4) {
    const float4* w0 = (const float4*)(W + (size_t)(c0 + 0) * 128);
    const float4* w1 = (const float4*)(W + (size_t)(c0 + 1) * 128);
    const float4* w2 = (const float4*)(W + (size_t)(c0 + 2) * 128);
    const float4* w3 = (const float4*)(W + (size_t)(c0 + 3) * 128);
    float h0a = 0.f, h0b = 0.f, h1a = 0.f, h1b = 0.f;
    float h2a = 0.f, h2b = 0.f, h3a = 0.f, h3b = 0.f;
#pragma unroll
    for (int i = 0; i < 32; ++i) {
      float4 xa = x[i];
      float4 v0 = w0[i], v1 = w1[i], v2 = w2[i], v3 = w3[i];
      h0a += xa.x * v0.x + xa.z * v0.z;  h0b += xa.y * v0.y + xa.w * v0.w;
      h1a += xa.x * v1.x + xa.z * v1.z;  h1b += xa.y * v1.y + xa.w * v1.w;
      h2a += xa.x * v2.x + xa.z * v2.z;  h2b += xa.y * v2.y + xa.w * v2.w;
      h3a += xa.x * v3.x + xa.z * v3.z;  h3b += xa.y * v3.y + xa.w * v3.w;
    }
    float h0 = fmaxf(h0a + h0b + B[c0 + 0], 0.f);
    float h1 = fmaxf(h1a + h1b + B[c0 + 1], 0.f);
    float h2 = fmaxf(h2a + h2b + B[c0 + 2], 0.f);
    float h3 = fmaxf(h3a + h3b + B[c0 + 3], 0.f);
#pragma unroll
    for (int o = 0; o < 16; ++o) {
      const float* wo = Wo + (size_t)o * 128 + c0;
      g[o] += h0 * wo[0] + h1 * wo[1] + h2 * wo[2] + h3 * wo[3];
    }
  }

  float* gr = G + (size_t)r * 16;
#pragma unroll
  for (int o = 0; o < 16; o += 4)
    *(float4*)(gr + o) = make_float4(g[o], g[o + 1], g[o + 2], g[o + 3]);
}

// ---------------- degree count (float, exact for counts < 2^24) ----------------------
__global__ void deg_count_kernel(const int* __restrict__ dst, float* __restrict__ deg, int E)
{
  int i = blockIdx.x * 256 + threadIdx.x;
  if (i < E) atomAddF(&deg[dst[i]], 1.0f);
}

// ---------------- 16-dim scatter-mean: T[dst] += G[src] / deg[dst] -------------------
// 4 lanes per edge (float4 each). 64 edges per block.
__global__ __launch_bounds__(256) void scatter16_kernel(
    const float* __restrict__ G, float* __restrict__ T,
    const int* __restrict__ src, const int* __restrict__ dst,
    const float* __restrict__ deg, int E)
{
  int e = blockIdx.x * 64 + (threadIdx.x >> 2);
  if (e >= E) return;
  int l4 = (threadIdx.x & 3) * 4;
  int s = src[e], d = dst[e];
  float scale = 1.0f / fmaxf(deg[d], 1.0f);
  float4 v = *(const float4*)(G + (size_t)s * 16 + l4);
  float* p = T + (size_t)d * 16 + l4;
  atomAddF(p + 0, v.x * scale);
  atomAddF(p + 1, v.y * scale);
  atomAddF(p + 2, v.z * scale);
  atomAddF(p + 3, v.w * scale);
}

// ---------------- dual scatter into out: out[dst] += (a*G[src] + c*T[src]) / deg[dst] --
__global__ __launch_bounds__(256) void scatter16_dual_kernel(
    const float* __restrict__ G, const float* __restrict__ T,
    float* __restrict__ out,
    const int* __restrict__ src, const int* __restrict__ dst,
    const float* __restrict__ deg, float a, float c, int E)
{
  int e = blockIdx.x * 64 + (threadIdx.x >> 2);
  if (e >= E) return;
  int l4 = (threadIdx.x & 3) * 4;
  int s = src[e], d = dst[e];
  float scale = 1.0f / fmaxf(deg[d], 1.0f);
  float4 g = *(const float4*)(G + (size_t)s * 16 + l4);
  float4 tt = *(const float4*)(T + (size_t)s * 16 + l4);
  float* p = out + (size_t)d * 16 + l4;
  atomAddF(p + 0, (a * g.x + c * tt.x) * scale);
  atomAddF(p + 1, (a * g.y + c * tt.y) * scale);
  atomAddF(p + 2, (a * g.z + c * tt.z) * scale);
  atomAddF(p + 3, (a * g.w + c * tt.w) * scale);
}

// ---------------- out init: out = alpha^2 * g_m + b_out ------------------------------
__global__ void init_out_kernel(const float* __restrict__ Gm, const float* __restrict__ bo,
                                float* __restrict__ out, int n)
{
  int i = blockIdx.x * 256 + threadIdx.x;
  if (i < n) out[i] = ALPHA * ALPHA * Gm[i] + bo[i & 15];
}

extern "C" void kernel_launch(void* const* d_in, const int* in_sizes, int n_in,
                              void* d_out, int out_size, void* d_ws, size_t ws_size,
                              hipStream_t stream)
{
  const float* x_user  = (const float*)d_in[0];
  const float* x_movie = (const float*)d_in[1];
  const float* x_dir   = (const float*)d_in[2];
  const int* rates_src = (const int*)d_in[3];
  const int* rates_dst = (const int*)d_in[4];
  const int* rby_src   = (const int*)d_in[5];
  const int* rby_dst   = (const int*)d_in[6];
  const int* dir_src   = (const int*)d_in[7];
  const int* dir_dst   = (const int*)d_in[8];
  const int* dby_src   = (const int*)d_in[9];
  const int* dby_dst   = (const int*)d_in[10];
  const float* W_user  = (const float*)d_in[11];
  const float* b_user  = (const float*)d_in[12];
  const float* W_movie = (const float*)d_in[13];
  const float* b_movie = (const float*)d_in[14];
  const float* W_dir   = (const float*)d_in[15];
  const float* b_dir   = (const float*)d_in[16];
  const float* W_out   = (const float*)d_in[17];
  const float* b_out   = (const float*)d_in[18];

  const int NU = in_sizes[0] / 128, NM = in_sizes[1] / 128, ND = in_sizes[2] / 128;
  const int Er = in_sizes[3], Erby = in_sizes[5], Edir = in_sizes[7], Edby = in_sizes[9];

  // ---- workspace layout (no H buffers anymore — projection is fused)
  char* w = (char*)d_ws;
  size_t off = 0;
  auto take = [&](size_t bytes) { char* p = w + off; off += (bytes + 255) & ~(size_t)255; return p; };
  float* g_u = (float*)take((size_t)NU * 16 * 4);
  float* g_m = (float*)take((size_t)NM * 16 * 4);
  float* g_d = (float*)take((size_t)ND * 16 * 4);
  // zero region start: t_u, t_d, 4 degree arrays (contiguous)
  size_t zero_begin = off;
  float* t_u     = (float*)take((size_t)NU * 16 * 4);
  float* t_d     = (float*)take((size_t)ND * 16 * 4);
  float* deg_r   = (float*)take((size_t)NM * 4);
  float* deg_dir = (float*)take((size_t)NM * 4);
  float* deg_rby = (float*)take((size_t)NU * 4);
  float* deg_dby = (float*)take((size_t)ND * 4);
  size_t zero_bytes = off - zero_begin;
  if (off > ws_size) return;

  // 1. zero accumulators + degree arrays
  hipMemsetAsync(w + zero_begin, 0, zero_bytes, stream);

  // 2. degree counts
  deg_count_kernel<<<(Er   + 255) / 256, 256, 0, stream>>>(rates_dst, deg_r,   Er);
  deg_count_kernel<<<(Edir + 255) / 256, 256, 0, stream>>>(dir_dst,   deg_dir, Edir);
  deg_count_kernel<<<(Erby + 255) / 256, 256, 0, stream>>>(rby_dst,   deg_rby, Erby);
  deg_count_kernel<<<(Edby + 255) / 256, 256, 0, stream>>>(dby_dst,   deg_dby, Edby);

  // 3. fused input linear + relu + projection to 16-dim output space
  fused_lin_proj_kernel<<<(NU + 255) / 256, 256, 0, stream>>>(x_user,  W_user,  b_user,  W_out, g_u, NU);
  fused_lin_proj_kernel<<<(NM + 255) / 256, 256, 0, stream>>>(x_movie, W_movie, b_movie, W_out, g_m, NM);
  fused_lin_proj_kernel<<<(ND + 255) / 256, 256, 0, stream>>>(x_dir,   W_dir,   b_dir,   W_out, g_d, ND);

  // 4. t_u = mean_rby(g_m) [user], t_d = mean_dby(g_m) [director]
  scatter16_kernel<<<(Erby + 63) / 64, 256, 0, stream>>>(g_m, t_u, rby_src, rby_dst, deg_rby, Erby);
  scatter16_kernel<<<(Edby + 63) / 64, 256, 0, stream>>>(g_m, t_d, dby_src, dby_dst, deg_dby, Edby);

  // 5. out = alpha^2 * g_m + b_out
  init_out_kernel<<<(NM * 16 + 255) / 256, 256, 0, stream>>>(g_m, b_out, (float*)d_out, NM * 16);

  // 6. out += mean_rates(alpha*g_u + 0.5*t_u) + mean_dir(alpha*g_d + 0.5*t_d)
  scatter16_dual_kernel<<<(Er + 63) / 64, 256, 0, stream>>>(
      g_u, t_u, (float*)d_out, rates_src, rates_dst, deg_r, ALPHA, 0.5f, Er);
  scatter16_dual_kernel<<<(Edir + 63) / 64, 256, 0, stream>>>(
      g_d, t_d, (float*)d_out, dir_src, dir_dst, deg_dir, ALPHA, 0.5f, Edir);
}

// Round 3
// 449.059 us; speedup vs baseline: 3.1486x; 2.7670x over previous
//
#include <hip/hip_runtime.h>

#define ALPHA 0.01f

typedef __attribute__((ext_vector_type(8))) short short8v;   // 8 x bf16 bits (4 VGPR)
typedef __attribute__((ext_vector_type(4))) float float4v;   // MFMA acc

__device__ __forceinline__ void atomAddF(float* p, float v) {
  unsafeAtomicAdd(p, v);  // native global_atomic_add_f32 on gfx950
}

// split fp32 -> bf16 hi + bf16 lo (truncation; residual capture => ~2^-24 total rel err)
__device__ __forceinline__ void bsplit(float x, unsigned short& hi, unsigned short& lo) {
  unsigned u = __float_as_uint(x);
  hi = (unsigned short)(u >> 16);
  float r = x - __uint_as_float(u & 0xFFFF0000u);
  lo = (unsigned short)(__float_as_uint(r) >> 16);
}

__device__ __forceinline__ void frag_from8(const float* v, short8v& hi, short8v& lo) {
#pragma unroll
  for (int e = 0; e < 8; ++e) {
    unsigned short h, l;
    bsplit(v[e], h, l);
    hi[e] = (short)h;
    lo[e] = (short)l;
  }
}

// ---------------- fused MFMA: G[N,16] = relu(X[N,128] @ W^T + b) @ Wo^T ---------------
// bf16x3 split for fp32-level accuracy. W hi/lo in swizzled LDS; X frags direct from
// global to registers; per-wave padded fp32 LDS buffer for the h transpose before the
// projection MFMA. Barrier-free grid-stride main loop; 2 blocks/CU.
__global__ __launch_bounds__(256, 2) void fused_mfma_kernel(
    const float* __restrict__ X, const float* __restrict__ W,
    const float* __restrict__ B, const float* __restrict__ Wo,
    float* __restrict__ G, int N)
{
  // LDS: [0,64K): Whi[128][128], Wlo[128][128] bf16 swizzled
  //      [64K, 64K+10368): Wo staging (transient 8K) then per-wave hbuf[32][17] f32
  __shared__ char smem[65536 + 10368] __attribute__((aligned(16)));
  unsigned short* Whi = (unsigned short*)smem;
  unsigned short* Wlo = (unsigned short*)(smem + 32768);
  unsigned short* WoHi = (unsigned short*)(smem + 65536);
  unsigned short* WoLo = (unsigned short*)(smem + 65536 + 4096);

  const int t = threadIdx.x;
  const int wave = t >> 6;
  const int lane = t & 63;
  const int s = lane & 15;        // frag row/col index
  const int q = lane >> 4;        // k-window quarter
  float* hbuf = (float*)(smem + 65536 + wave * 2176);  // [32][17] f32, per-wave

  // ---- stage W (hi/lo, swizzled) : 8192 col-pairs over 256 threads
#pragma unroll
  for (int i = 0; i < 32; ++i) {
    int p = i * 256 + t;
    int row = p >> 6, c2 = p & 63;
    float w0 = W[row * 128 + c2 * 2];
    float w1 = W[row * 128 + c2 * 2 + 1];
    unsigned short h0, l0, h1, l1;
    bsplit(w0, h0, l0); bsplit(w1, h1, l1);
    int u32idx = row * 64 + ((((c2 * 4) ^ ((row & 7) << 4))) >> 2);
    ((unsigned*)Whi)[u32idx] = (unsigned)h0 | ((unsigned)h1 << 16);
    ((unsigned*)Wlo)[u32idx] = (unsigned)l0 | ((unsigned)l1 << 16);
  }
  // ---- stage Wo (hi/lo, swizzled): 1024 col-pairs
#pragma unroll
  for (int i = 0; i < 4; ++i) {
    int p = i * 256 + t;
    int row = p >> 6, c2 = p & 63;
    float w0 = Wo[row * 128 + c2 * 2];
    float w1 = Wo[row * 128 + c2 * 2 + 1];
    unsigned short h0, l0, h1, l1;
    bsplit(w0, h0, l0); bsplit(w1, h1, l1);
    int u32idx = row * 64 + ((((c2 * 4) ^ ((row & 7) << 4))) >> 2);
    ((unsigned*)WoHi)[u32idx] = (unsigned)h0 | ((unsigned)h1 << 16);
    ((unsigned*)WoLo)[u32idx] = (unsigned)l0 | ((unsigned)l1 << 16);
  }
  __syncthreads();

  // ---- hoist Wo fragments to registers (B-operand: lane <- Wo[o=s][k=ks*32+q*8..+8])
  short8v woh[4], wol[4];
  const int woswz = (s & 7) << 4;
#pragma unroll
  for (int ks = 0; ks < 4; ++ks) {
    int off = s * 256 + ((ks * 64 + q * 16) ^ woswz);
    woh[ks] = *(const short8v*)((char*)WoHi + off);
    wol[ks] = *(const short8v*)((char*)WoLo + off);
  }
  // ---- hoist bias values for this lane's h-columns
  float bv[8];
#pragma unroll
  for (int nt = 0; nt < 8; ++nt) bv[nt] = B[nt * 16 + s];
  __syncthreads();  // Wo staging area now reusable as hbuf

  const int nchunks = (N + 127) >> 7;
  const int bswz = (s & 7) << 4;  // W row swizzle: rows c have (c&7)==(s&7)

  for (int chunk = blockIdx.x; chunk < nchunks; chunk += gridDim.x) {
    const int rowbase = chunk * 128 + wave * 32;

    // ---- load x fragments (A-operand) straight from global, convert to hi/lo
    short8v ahi[2][4], alo[2][4];
#pragma unroll
    for (int mt = 0; mt < 2; ++mt) {
      int row = rowbase + mt * 16 + s;
      int crow = row < N ? row : (N - 1);           // clamp (results unused for OOB)
      const float* xr = X + (size_t)crow * 128;
#pragma unroll
      for (int ks = 0; ks < 4; ++ks) {
        float4 f0 = *(const float4*)(xr + ks * 32 + q * 8);
        float4 f1 = *(const float4*)(xr + ks * 32 + q * 8 + 4);
        float v[8] = {f0.x, f0.y, f0.z, f0.w, f1.x, f1.y, f1.z, f1.w};
        frag_from8(v, ahi[mt][ks], alo[mt][ks]);
      }
    }

    // ---- main GEMM: h = x @ W^T  (bf16x3), acc[mt][nt] = 16x16 tile
    float4v acc[2][8];
#pragma unroll
    for (int mt = 0; mt < 2; ++mt)
#pragma unroll
      for (int nt = 0; nt < 8; ++nt) acc[mt][nt] = (float4v){0.f, 0.f, 0.f, 0.f};

#pragma unroll
    for (int ks = 0; ks < 4; ++ks) {
      short8v bh[8];
#pragma unroll
      for (int nt = 0; nt < 8; ++nt) {
        int c = nt * 16 + s;
        int off = c * 256 + ((ks * 64 + q * 16) ^ bswz);
        bh[nt] = *(const short8v*)((char*)Whi + off);
      }
#pragma unroll
      for (int nt = 0; nt < 8; ++nt) {
#pragma unroll
        for (int mt = 0; mt < 2; ++mt) {
          acc[mt][nt] = __builtin_amdgcn_mfma_f32_16x16x32_bf16(ahi[mt][ks], bh[nt], acc[mt][nt], 0, 0, 0);
          acc[mt][nt] = __builtin_amdgcn_mfma_f32_16x16x32_bf16(alo[mt][ks], bh[nt], acc[mt][nt], 0, 0, 0);
        }
      }
#pragma unroll
      for (int nt = 0; nt < 8; ++nt) {
        int c = nt * 16 + s;
        int off = c * 256 + ((ks * 64 + q * 16) ^ bswz);
        short8v bl = *(const short8v*)((char*)Wlo + off);
#pragma unroll
        for (int mt = 0; mt < 2; ++mt)
          acc[mt][nt] = __builtin_amdgcn_mfma_f32_16x16x32_bf16(ahi[mt][ks], bl, acc[mt][nt], 0, 0, 0);
      }
    }

    // ---- projection: g = relu(h + b) @ Wo^T, via per-wave LDS transpose (fp32 [32][17])
#pragma unroll
    for (int mt = 0; mt < 2; ++mt) {
      float4v gacc = (float4v){0.f, 0.f, 0.f, 0.f};
#pragma unroll
      for (int ks = 0; ks < 4; ++ks) {
        // write the two n-tiles covering cols [ks*32, ks*32+32): hbuf[c_local][r]
#pragma unroll
        for (int j = 0; j < 2; ++j) {
          int nt = 2 * ks + j;
          int cl = j * 16 + s;
#pragma unroll
          for (int e = 0; e < 4; ++e)
            hbuf[cl * 17 + q * 4 + e] = fmaxf(acc[mt][nt][e] + bv[nt], 0.f);
        }
        // read back in A-frag layout: lane <- h[row=s][k=ks*32+q*8+e]
        float hv[8];
#pragma unroll
        for (int e = 0; e < 8; ++e) hv[e] = hbuf[(q * 8 + e) * 17 + s];
        short8v hh, hl;
        frag_from8(hv, hh, hl);
        gacc = __builtin_amdgcn_mfma_f32_16x16x32_bf16(hh, woh[ks], gacc, 0, 0, 0);
        gacc = __builtin_amdgcn_mfma_f32_16x16x32_bf16(hl, woh[ks], gacc, 0, 0, 0);
        gacc = __builtin_amdgcn_mfma_f32_16x16x32_bf16(hh, wol[ks], gacc, 0, 0, 0);
      }
      // write G: lane holds g[row=4q+e][o=s]
      int grow = rowbase + mt * 16 + 4 * q;
#pragma unroll
      for (int e = 0; e < 4; ++e)
        if (grow + e < N) G[(size_t)(grow + e) * 16 + s] = gacc[e];
    }
  }
}

// ---------------- degree count (float, exact for counts < 2^24) ----------------------
__global__ void deg_count_kernel(const int* __restrict__ dst, float* __restrict__ deg, int E)
{
  int i = blockIdx.x * 256 + threadIdx.x;
  if (i < E) atomAddF(&deg[dst[i]], 1.0f);
}

// ---------------- 16-dim scatter-mean: T[dst] += G[src] / deg[dst] -------------------
__global__ __launch_bounds__(256) void scatter16_kernel(
    const float* __restrict__ G, float* __restrict__ T,
    const int* __restrict__ src, const int* __restrict__ dst,
    const float* __restrict__ deg, int E)
{
  int e = blockIdx.x * 64 + (threadIdx.x >> 2);
  if (e >= E) return;
  int l4 = (threadIdx.x & 3) * 4;
  int s = src[e], d = dst[e];
  float scale = 1.0f / fmaxf(deg[d], 1.0f);
  float4 v = *(const float4*)(G + (size_t)s * 16 + l4);
  float* p = T + (size_t)d * 16 + l4;
  atomAddF(p + 0, v.x * scale);
  atomAddF(p + 1, v.y * scale);
  atomAddF(p + 2, v.z * scale);
  atomAddF(p + 3, v.w * scale);
}

// ---------------- dual scatter into out: out[dst] += (a*G[src] + c*T[src]) / deg[dst] --
__global__ __launch_bounds__(256) void scatter16_dual_kernel(
    const float* __restrict__ G, const float* __restrict__ T,
    float* __restrict__ out,
    const int* __restrict__ src, const int* __restrict__ dst,
    const float* __restrict__ deg, float a, float c, int E)
{
  int e = blockIdx.x * 64 + (threadIdx.x >> 2);
  if (e >= E) return;
  int l4 = (threadIdx.x & 3) * 4;
  int s = src[e], d = dst[e];
  float scale = 1.0f / fmaxf(deg[d], 1.0f);
  float4 g = *(const float4*)(G + (size_t)s * 16 + l4);
  float4 tt = *(const float4*)(T + (size_t)s * 16 + l4);
  float* p = out + (size_t)d * 16 + l4;
  atomAddF(p + 0, (a * g.x + c * tt.x) * scale);
  atomAddF(p + 1, (a * g.y + c * tt.y) * scale);
  atomAddF(p + 2, (a * g.z + c * tt.z) * scale);
  atomAddF(p + 3, (a * g.w + c * tt.w) * scale);
}

// ---------------- out init: out = alpha^2 * g_m + b_out ------------------------------
__global__ void init_out_kernel(const float* __restrict__ Gm, const float* __restrict__ bo,
                                float* __restrict__ out, int n)
{
  int i = blockIdx.x * 256 + threadIdx.x;
  if (i < n) out[i] = ALPHA * ALPHA * Gm[i] + bo[i & 15];
}

extern "C" void kernel_launch(void* const* d_in, const int* in_sizes, int n_in,
                              void* d_out, int out_size, void* d_ws, size_t ws_size,
                              hipStream_t stream)
{
  const float* x_user  = (const float*)d_in[0];
  const float* x_movie = (const float*)d_in[1];
  const float* x_dir   = (const float*)d_in[2];
  const int* rates_src = (const int*)d_in[3];
  const int* rates_dst = (const int*)d_in[4];
  const int* rby_src   = (const int*)d_in[5];
  const int* rby_dst   = (const int*)d_in[6];
  const int* dir_src   = (const int*)d_in[7];
  const int* dir_dst   = (const int*)d_in[8];
  const int* dby_src   = (const int*)d_in[9];
  const int* dby_dst   = (const int*)d_in[10];
  const float* W_user  = (const float*)d_in[11];
  const float* b_user  = (const float*)d_in[12];
  const float* W_movie = (const float*)d_in[13];
  const float* b_movie = (const float*)d_in[14];
  const float* W_dir   = (const float*)d_in[15];
  const float* b_dir   = (const float*)d_in[16];
  const float* W_out   = (const float*)d_in[17];
  const float* b_out   = (const float*)d_in[18];

  const int NU = in_sizes[0] / 128, NM = in_sizes[1] / 128, ND = in_sizes[2] / 128;
  const int Er = in_sizes[3], Erby = in_sizes[5], Edir = in_sizes[7], Edby = in_sizes[9];

  // ---- workspace layout
  char* w = (char*)d_ws;
  size_t off = 0;
  auto take = [&](size_t bytes) { char* p = w + off; off += (bytes + 255) & ~(size_t)255; return p; };
  float* g_u = (float*)take((size_t)NU * 16 * 4);
  float* g_m = (float*)take((size_t)NM * 16 * 4);
  float* g_d = (float*)take((size_t)ND * 16 * 4);
  size_t zero_begin = off;
  float* t_u     = (float*)take((size_t)NU * 16 * 4);
  float* t_d     = (float*)take((size_t)ND * 16 * 4);
  float* deg_r   = (float*)take((size_t)NM * 4);
  float* deg_dir = (float*)take((size_t)NM * 4);
  float* deg_rby = (float*)take((size_t)NU * 4);
  float* deg_dby = (float*)take((size_t)ND * 4);
  size_t zero_bytes = off - zero_begin;
  if (off > ws_size) return;

  // 1. zero accumulators + degree arrays
  hipMemsetAsync(w + zero_begin, 0, zero_bytes, stream);

  // 2. degree counts
  deg_count_kernel<<<(Er   + 255) / 256, 256, 0, stream>>>(rates_dst, deg_r,   Er);
  deg_count_kernel<<<(Edir + 255) / 256, 256, 0, stream>>>(dir_dst,   deg_dir, Edir);
  deg_count_kernel<<<(Erby + 255) / 256, 256, 0, stream>>>(rby_dst,   deg_rby, Erby);
  deg_count_kernel<<<(Edby + 255) / 256, 256, 0, stream>>>(dby_dst,   deg_dby, Edby);

  // 3. fused MFMA linear+relu+projection (grid-stride over 128-row chunks)
  auto grid_for = [](int n) { int c = (n + 127) >> 7; return c < 512 ? c : 512; };
  fused_mfma_kernel<<<grid_for(NU), 256, 0, stream>>>(x_user,  W_user,  b_user,  W_out, g_u, NU);
  fused_mfma_kernel<<<grid_for(NM), 256, 0, stream>>>(x_movie, W_movie, b_movie, W_out, g_m, NM);
  fused_mfma_kernel<<<grid_for(ND), 256, 0, stream>>>(x_dir,   W_dir,   b_dir,   W_out, g_d, ND);

  // 4. t_u = mean_rby(g_m) [user], t_d = mean_dby(g_m) [director]
  scatter16_kernel<<<(Erby + 63) / 64, 256, 0, stream>>>(g_m, t_u, rby_src, rby_dst, deg_rby, Erby);
  scatter16_kernel<<<(Edby + 63) / 64, 256, 0, stream>>>(g_m, t_d, dby_src, dby_dst, deg_dby, Edby);

  // 5. out = alpha^2 * g_m + b_out
  init_out_kernel<<<(NM * 16 + 255) / 256, 256, 0, stream>>>(g_m, b_out, (float*)d_out, NM * 16);

  // 6. out += mean_rates(alpha*g_u + 0.5*t_u) + mean_dir(alpha*g_d + 0.5*t_d)
  scatter16_dual_kernel<<<(Er + 63) / 64, 256, 0, stream>>>(
      g_u, t_u, (float*)d_out, rates_src, rates_dst, deg_r, ALPHA, 0.5f, Er);
  scatter16_dual_kernel<<<(Edir + 63) / 64, 256, 0, stream>>>(
      g_d, t_d, (float*)d_out, dir_src, dir_dst, deg_dir, ALPHA, 0.5f, Edir);
}

// Round 4
// 313.090 us; speedup vs baseline: 4.5160x; 1.4343x over previous
//
#include <hip/hip_runtime.h>

#define ALPHA 0.01f

typedef __attribute__((ext_vector_type(8))) short short8v;   // 8 x bf16 bits (4 VGPR)
typedef __attribute__((ext_vector_type(4))) float float4v;   // MFMA acc

// split fp32 -> bf16 hi + bf16 lo (truncation; residual capture => ~2^-24 total rel err)
__device__ __forceinline__ void bsplit(float x, unsigned short& hi, unsigned short& lo) {
  unsigned u = __float_as_uint(x);
  hi = (unsigned short)(u >> 16);
  float r = x - __uint_as_float(u & 0xFFFF0000u);
  lo = (unsigned short)(__float_as_uint(r) >> 16);
}

__device__ __forceinline__ void frag_from8(const float* v, short8v& hi, short8v& lo) {
#pragma unroll
  for (int e = 0; e < 8; ++e) {
    unsigned short h, l;
    bsplit(v[e], h, l);
    hi[e] = (short)h;
    lo[e] = (short)l;
  }
}

// ---------------- fused MFMA: G[N,16] = relu(X[N,128] @ W^T + b) @ Wo^T ---------------
__global__ __launch_bounds__(256, 2) void fused_mfma_kernel(
    const float* __restrict__ X, const float* __restrict__ W,
    const float* __restrict__ B, const float* __restrict__ Wo,
    float* __restrict__ G, int N)
{
  __shared__ char smem[65536 + 10368] __attribute__((aligned(16)));
  unsigned short* Whi = (unsigned short*)smem;
  unsigned short* Wlo = (unsigned short*)(smem + 32768);
  unsigned short* WoHi = (unsigned short*)(smem + 65536);
  unsigned short* WoLo = (unsigned short*)(smem + 65536 + 4096);

  const int t = threadIdx.x;
  const int wave = t >> 6;
  const int lane = t & 63;
  const int s = lane & 15;
  const int q = lane >> 4;
  float* hbuf = (float*)(smem + 65536 + wave * 2176);  // [32][17] f32, per-wave

#pragma unroll
  for (int i = 0; i < 32; ++i) {
    int p = i * 256 + t;
    int row = p >> 6, c2 = p & 63;
    float w0 = W[row * 128 + c2 * 2];
    float w1 = W[row * 128 + c2 * 2 + 1];
    unsigned short h0, l0, h1, l1;
    bsplit(w0, h0, l0); bsplit(w1, h1, l1);
    int u32idx = row * 64 + ((((c2 * 4) ^ ((row & 7) << 4))) >> 2);
    ((unsigned*)Whi)[u32idx] = (unsigned)h0 | ((unsigned)h1 << 16);
    ((unsigned*)Wlo)[u32idx] = (unsigned)l0 | ((unsigned)l1 << 16);
  }
#pragma unroll
  for (int i = 0; i < 4; ++i) {
    int p = i * 256 + t;
    int row = p >> 6, c2 = p & 63;
    float w0 = Wo[row * 128 + c2 * 2];
    float w1 = Wo[row * 128 + c2 * 2 + 1];
    unsigned short h0, l0, h1, l1;
    bsplit(w0, h0, l0); bsplit(w1, h1, l1);
    int u32idx = row * 64 + ((((c2 * 4) ^ ((row & 7) << 4))) >> 2);
    ((unsigned*)WoHi)[u32idx] = (unsigned)h0 | ((unsigned)h1 << 16);
    ((unsigned*)WoLo)[u32idx] = (unsigned)l0 | ((unsigned)l1 << 16);
  }
  __syncthreads();

  short8v woh[4], wol[4];
  const int woswz = (s & 7) << 4;
#pragma unroll
  for (int ks = 0; ks < 4; ++ks) {
    int off = s * 256 + ((ks * 64 + q * 16) ^ woswz);
    woh[ks] = *(const short8v*)((char*)WoHi + off);
    wol[ks] = *(const short8v*)((char*)WoLo + off);
  }
  float bv[8];
#pragma unroll
  for (int nt = 0; nt < 8; ++nt) bv[nt] = B[nt * 16 + s];
  __syncthreads();  // Wo staging area now reusable as hbuf

  const int nchunks = (N + 127) >> 7;
  const int bswz = (s & 7) << 4;

  for (int chunk = blockIdx.x; chunk < nchunks; chunk += gridDim.x) {
    const int rowbase = chunk * 128 + wave * 32;

    short8v ahi[2][4], alo[2][4];
#pragma unroll
    for (int mt = 0; mt < 2; ++mt) {
      int row = rowbase + mt * 16 + s;
      int crow = row < N ? row : (N - 1);
      const float* xr = X + (size_t)crow * 128;
#pragma unroll
      for (int ks = 0; ks < 4; ++ks) {
        float4 f0 = *(const float4*)(xr + ks * 32 + q * 8);
        float4 f1 = *(const float4*)(xr + ks * 32 + q * 8 + 4);
        float v[8] = {f0.x, f0.y, f0.z, f0.w, f1.x, f1.y, f1.z, f1.w};
        frag_from8(v, ahi[mt][ks], alo[mt][ks]);
      }
    }

    float4v acc[2][8];
#pragma unroll
    for (int mt = 0; mt < 2; ++mt)
#pragma unroll
      for (int nt = 0; nt < 8; ++nt) acc[mt][nt] = (float4v){0.f, 0.f, 0.f, 0.f};

#pragma unroll
    for (int ks = 0; ks < 4; ++ks) {
      short8v bh[8];
#pragma unroll
      for (int nt = 0; nt < 8; ++nt) {
        int c = nt * 16 + s;
        int off = c * 256 + ((ks * 64 + q * 16) ^ bswz);
        bh[nt] = *(const short8v*)((char*)Whi + off);
      }
#pragma unroll
      for (int nt = 0; nt < 8; ++nt) {
#pragma unroll
        for (int mt = 0; mt < 2; ++mt) {
          acc[mt][nt] = __builtin_amdgcn_mfma_f32_16x16x32_bf16(ahi[mt][ks], bh[nt], acc[mt][nt], 0, 0, 0);
          acc[mt][nt] = __builtin_amdgcn_mfma_f32_16x16x32_bf16(alo[mt][ks], bh[nt], acc[mt][nt], 0, 0, 0);
        }
      }
#pragma unroll
      for (int nt = 0; nt < 8; ++nt) {
        int c = nt * 16 + s;
        int off = c * 256 + ((ks * 64 + q * 16) ^ bswz);
        short8v bl = *(const short8v*)((char*)Wlo + off);
#pragma unroll
        for (int mt = 0; mt < 2; ++mt)
          acc[mt][nt] = __builtin_amdgcn_mfma_f32_16x16x32_bf16(ahi[mt][ks], bl, acc[mt][nt], 0, 0, 0);
      }
    }

#pragma unroll
    for (int mt = 0; mt < 2; ++mt) {
      float4v gacc = (float4v){0.f, 0.f, 0.f, 0.f};
#pragma unroll
      for (int ks = 0; ks < 4; ++ks) {
#pragma unroll
        for (int j = 0; j < 2; ++j) {
          int nt = 2 * ks + j;
          int cl = j * 16 + s;
#pragma unroll
          for (int e = 0; e < 4; ++e)
            hbuf[cl * 17 + q * 4 + e] = fmaxf(acc[mt][nt][e] + bv[nt], 0.f);
        }
        float hv[8];
#pragma unroll
        for (int e = 0; e < 8; ++e) hv[e] = hbuf[(q * 8 + e) * 17 + s];
        short8v hh, hl;
        frag_from8(hv, hh, hl);
        gacc = __builtin_amdgcn_mfma_f32_16x16x32_bf16(hh, woh[ks], gacc, 0, 0, 0);
        gacc = __builtin_amdgcn_mfma_f32_16x16x32_bf16(hl, woh[ks], gacc, 0, 0, 0);
        gacc = __builtin_amdgcn_mfma_f32_16x16x32_bf16(hh, wol[ks], gacc, 0, 0, 0);
      }
      int grow = rowbase + mt * 16 + 4 * q;
#pragma unroll
      for (int e = 0; e < 4; ++e)
        if (grow + e < N) G[(size_t)(grow + e) * 16 + s] = gacc[e];
    }
  }
}

// ---------------- CSR build: combined histogram over 4 etypes -------------------------
// concat dst space: [0,NM)=rates, [NM,2NM)=dir, [2NM,2NM+NU)=rby, [2NM+NU,+ND)=dby
__global__ __launch_bounds__(256) void hist_kernel(
    const int* __restrict__ rd, const int* __restrict__ dd,
    const int* __restrict__ yd, const int* __restrict__ bd,
    int Er, int Edir, int Erby, int Edby, int NM, int NU,
    int* __restrict__ hist)
{
  int i = blockIdx.x * 256 + threadIdx.x;
  int c;
  if (i < Er) c = rd[i];
  else if (i < Er + Edir) c = NM + dd[i - Er];
  else if (i < Er + Edir + Erby) c = 2 * NM + yd[i - Er - Edir];
  else if (i < Er + Edir + Erby + Edby) c = 2 * NM + NU + bd[i - Er - Edir - Erby];
  else return;
  atomicAdd(&hist[c], 1);
}

// ---------------- 3-kernel exclusive scan over hist[H] -------------------------------
__global__ __launch_bounds__(256) void scan1_kernel(const int* __restrict__ hist,
                                                    int* __restrict__ bsum, int n)
{
  __shared__ int red[256];
  int i = blockIdx.x * 256 + threadIdx.x;
  red[threadIdx.x] = (i < n) ? hist[i] : 0;
  __syncthreads();
  for (int s = 128; s > 0; s >>= 1) {
    if (threadIdx.x < s) red[threadIdx.x] += red[threadIdx.x + s];
    __syncthreads();
  }
  if (threadIdx.x == 0) bsum[blockIdx.x] = red[0];
}

__global__ __launch_bounds__(1024) void scan2_kernel(int* __restrict__ bsum, int nB)
{
  __shared__ int tmp[1024];
  __shared__ int carry;
  if (threadIdx.x == 0) carry = 0;
  for (int base = 0; base < nB; base += 1024) {
    __syncthreads();
    int cl = carry;
    int i = base + threadIdx.x;
    int v = (i < nB) ? bsum[i] : 0;
    tmp[threadIdx.x] = v;
    __syncthreads();
    for (int d = 1; d < 1024; d <<= 1) {
      int add = (threadIdx.x >= (unsigned)d) ? tmp[threadIdx.x - d] : 0;
      __syncthreads();
      tmp[threadIdx.x] += add;
      __syncthreads();
    }
    int incl = tmp[threadIdx.x];
    if (i < nB) bsum[i] = incl - v + cl;
    __syncthreads();
    if (threadIdx.x == 1023) carry = cl + incl;
  }
}

__global__ __launch_bounds__(256) void scan3_kernel(
    const int* __restrict__ hist, const int* __restrict__ bsum,
    int* __restrict__ offs, int* __restrict__ cursor, int n)
{
  __shared__ int tmp[256];
  int i = blockIdx.x * 256 + threadIdx.x;
  int v = (i < n) ? hist[i] : 0;
  tmp[threadIdx.x] = v;
  __syncthreads();
  for (int d = 1; d < 256; d <<= 1) {
    int add = (threadIdx.x >= (unsigned)d) ? tmp[threadIdx.x - d] : 0;
    __syncthreads();
    tmp[threadIdx.x] += add;
    __syncthreads();
  }
  int excl = tmp[threadIdx.x] - v + bsum[blockIdx.x];
  if (i < n) { offs[i] = excl; cursor[i] = excl; }
}

// ---------------- ticket fill: sorted_src[bucket slots] = src -------------------------
__global__ __launch_bounds__(256) void ticket_kernel(
    const int* __restrict__ rs, const int* __restrict__ rd,
    const int* __restrict__ ds, const int* __restrict__ dd,
    const int* __restrict__ ys, const int* __restrict__ yd,
    const int* __restrict__ bs, const int* __restrict__ bd,
    int Er, int Edir, int Erby, int Edby, int NM, int NU,
    int* __restrict__ cursor, int* __restrict__ sorted_src)
{
  int i = blockIdx.x * 256 + threadIdx.x;
  int c, s;
  if (i < Er) { s = rs[i]; c = rd[i]; }
  else if (i < Er + Edir) { int j = i - Er; s = ds[j]; c = NM + dd[j]; }
  else if (i < Er + Edir + Erby) { int j = i - Er - Edir; s = ys[j]; c = 2 * NM + yd[j]; }
  else if (i < Er + Edir + Erby + Edby) { int j = i - Er - Edir - Erby; s = bs[j]; c = 2 * NM + NU + bd[j]; }
  else return;
  int p = atomicAdd(&cursor[c], 1);
  sorted_src[p] = s;
}

// ---------------- pay[node] = ALPHA*g_self[node] + 0.5*mean_CSR(g_src) ----------------
// 16 lanes per node (one per feature); per edge: one coalesced 64B read of g_src[s].
__global__ __launch_bounds__(256) void gather_pay_kernel(
    const float* __restrict__ g_src, const float* __restrict__ g_self,
    const int* __restrict__ offs, const int* __restrict__ hist, int nb,
    const int* __restrict__ sorted_src, float* __restrict__ pay, int n)
{
  int tid = blockIdx.x * 256 + threadIdx.x;
  int node = tid >> 4, o = tid & 15;
  if (node >= n) return;
  int start = offs[nb + node], cnt = hist[nb + node];
  float sum = 0.f;
  for (int j = 0; j < cnt; ++j) {
    int s = sorted_src[start + j];
    sum += g_src[(size_t)s * 16 + o];
  }
  pay[(size_t)node * 16 + o] =
      ALPHA * g_self[(size_t)node * 16 + o] + 0.5f * sum / fmaxf((float)cnt, 1.f);
}

// ---------------- out[m] = b_out + a^2*g_m[m] + mean_rates(pay_u) + mean_dir(pay_d) ---
__global__ __launch_bounds__(256) void final_kernel(
    const float* __restrict__ gm, const float* __restrict__ pay_u,
    const float* __restrict__ pay_d,
    const int* __restrict__ offs, const int* __restrict__ hist,
    const int* __restrict__ sorted_src,
    const float* __restrict__ bo, float* __restrict__ out, int NM)
{
  int tid = blockIdx.x * 256 + threadIdx.x;
  int m = tid >> 4, o = tid & 15;
  if (m >= NM) return;
  int s0 = offs[m], c0 = hist[m];
  float sr = 0.f;
  for (int j = 0; j < c0; ++j) sr += pay_u[(size_t)sorted_src[s0 + j] * 16 + o];
  int s1 = offs[NM + m], c1 = hist[NM + m];
  float sd = 0.f;
  for (int j = 0; j < c1; ++j) sd += pay_d[(size_t)sorted_src[s1 + j] * 16 + o];
  out[(size_t)m * 16 + o] = bo[o] + ALPHA * ALPHA * gm[(size_t)m * 16 + o]
                          + sr / fmaxf((float)c0, 1.f) + sd / fmaxf((float)c1, 1.f);
}

extern "C" void kernel_launch(void* const* d_in, const int* in_sizes, int n_in,
                              void* d_out, int out_size, void* d_ws, size_t ws_size,
                              hipStream_t stream)
{
  const float* x_user  = (const float*)d_in[0];
  const float* x_movie = (const float*)d_in[1];
  const float* x_dir   = (const float*)d_in[2];
  const int* rates_src = (const int*)d_in[3];
  const int* rates_dst = (const int*)d_in[4];
  const int* rby_src   = (const int*)d_in[5];
  const int* rby_dst   = (const int*)d_in[6];
  const int* dir_src   = (const int*)d_in[7];
  const int* dir_dst   = (const int*)d_in[8];
  const int* dby_src   = (const int*)d_in[9];
  const int* dby_dst   = (const int*)d_in[10];
  const float* W_user  = (const float*)d_in[11];
  const float* b_user  = (const float*)d_in[12];
  const float* W_movie = (const float*)d_in[13];
  const float* b_movie = (const float*)d_in[14];
  const float* W_dir   = (const float*)d_in[15];
  const float* b_dir   = (const float*)d_in[16];
  const float* W_out   = (const float*)d_in[17];
  const float* b_out   = (const float*)d_in[18];

  const int NU = in_sizes[0] / 128, NM = in_sizes[1] / 128, ND = in_sizes[2] / 128;
  const int Er = in_sizes[3], Erby = in_sizes[5], Edir = in_sizes[7], Edby = in_sizes[9];
  const int Etot = Er + Edir + Erby + Edby;
  const int H = 2 * NM + NU + ND;                 // concat dst space
  const int nScanBlk = (H + 255) / 256;

  // ---- workspace layout
  char* w = (char*)d_ws;
  size_t off = 0;
  auto take = [&](size_t bytes) { char* p = w + off; off += (bytes + 255) & ~(size_t)255; return p; };
  float* g_u   = (float*)take((size_t)NU * 16 * 4);
  float* g_m   = (float*)take((size_t)NM * 16 * 4);
  float* g_d   = (float*)take((size_t)ND * 16 * 4);
  float* pay_u = (float*)take((size_t)NU * 16 * 4);
  float* pay_d = (float*)take((size_t)ND * 16 * 4);
  int* hist    = (int*)take((size_t)H * 4);        // zeroed
  int* offs    = (int*)take((size_t)H * 4);
  int* cursor  = (int*)take((size_t)H * 4);
  int* bsum    = (int*)take((size_t)nScanBlk * 4);
  int* ssrc    = (int*)take((size_t)Etot * 4);
  if (off > ws_size) return;

  // 1. zero histogram
  hipMemsetAsync(hist, 0, (size_t)H * 4, stream);

  // 2. combined histogram (also serves as degree arrays)
  hist_kernel<<<(Etot + 255) / 256, 256, 0, stream>>>(
      rates_dst, dir_dst, rby_dst, dby_dst, Er, Edir, Erby, Edby, NM, NU, hist);

  // 3. exclusive scan -> offs, cursor
  scan1_kernel<<<nScanBlk, 256, 0, stream>>>(hist, bsum, H);
  scan2_kernel<<<1, 1024, 0, stream>>>(bsum, nScanBlk);
  scan3_kernel<<<nScanBlk, 256, 0, stream>>>(hist, bsum, offs, cursor, H);

  // 4. ticket fill of sorted src lists
  ticket_kernel<<<(Etot + 255) / 256, 256, 0, stream>>>(
      rates_src, rates_dst, dir_src, dir_dst, rby_src, rby_dst, dby_src, dby_dst,
      Er, Edir, Erby, Edby, NM, NU, cursor, ssrc);

  // 5. fused MFMA linear+relu+projection
  auto grid_for = [](int n) { int c = (n + 127) >> 7; return c < 512 ? c : 512; };
  fused_mfma_kernel<<<grid_for(NU), 256, 0, stream>>>(x_user,  W_user,  b_user,  W_out, g_u, NU);
  fused_mfma_kernel<<<grid_for(NM), 256, 0, stream>>>(x_movie, W_movie, b_movie, W_out, g_m, NM);
  fused_mfma_kernel<<<grid_for(ND), 256, 0, stream>>>(x_dir,   W_dir,   b_dir,   W_out, g_d, ND);

  // 6. pay_u = a*g_u + 0.5*mean_rby(g_m);  pay_d = a*g_d + 0.5*mean_dby(g_m)
  gather_pay_kernel<<<(NU * 16 + 255) / 256, 256, 0, stream>>>(
      g_m, g_u, offs, hist, 2 * NM, ssrc, pay_u, NU);
  gather_pay_kernel<<<(ND * 16 + 255) / 256, 256, 0, stream>>>(
      g_m, g_d, offs, hist, 2 * NM + NU, ssrc, pay_d, ND);

  // 7. out = b_out + a^2*g_m + mean_rates(pay_u) + mean_dir(pay_d)
  final_kernel<<<(NM * 16 + 255) / 256, 256, 0, stream>>>(
      g_m, pay_u, pay_d, offs, hist, ssrc, b_out, (float*)d_out, NM);
}

// Round 5
// 279.651 us; speedup vs baseline: 5.0560x; 1.1196x over previous
//
#include <hip/hip_runtime.h>

#define ALPHA 0.01f

typedef __attribute__((ext_vector_type(8))) short short8v;   // 8 x bf16 bits (4 VGPR)
typedef __attribute__((ext_vector_type(4))) float float4v;   // MFMA acc

// split fp32 -> bf16 hi + bf16 lo (truncation; residual capture => ~2^-24 total rel err)
__device__ __forceinline__ void bsplit(float x, unsigned short& hi, unsigned short& lo) {
  unsigned u = __float_as_uint(x);
  hi = (unsigned short)(u >> 16);
  float r = x - __uint_as_float(u & 0xFFFF0000u);
  lo = (unsigned short)(__float_as_uint(r) >> 16);
}

__device__ __forceinline__ void frag_from8(const float* v, short8v& hi, short8v& lo) {
#pragma unroll
  for (int e = 0; e < 8; ++e) {
    unsigned short h, l;
    bsplit(v[e], h, l);
    hi[e] = (short)h;
    lo[e] = (short)l;
  }
}

// ---------------- fused MFMA: G[N,16] = relu(X[N,128] @ W^T + b) @ Wo^T ---------------
__global__ __launch_bounds__(256, 2) void fused_mfma_kernel(
    const float* __restrict__ X, const float* __restrict__ W,
    const float* __restrict__ B, const float* __restrict__ Wo,
    float* __restrict__ G, int N)
{
  __shared__ char smem[65536 + 10368] __attribute__((aligned(16)));
  unsigned short* Whi = (unsigned short*)smem;
  unsigned short* Wlo = (unsigned short*)(smem + 32768);
  unsigned short* WoHi = (unsigned short*)(smem + 65536);
  unsigned short* WoLo = (unsigned short*)(smem + 65536 + 4096);

  const int t = threadIdx.x;
  const int wave = t >> 6;
  const int lane = t & 63;
  const int s = lane & 15;
  const int q = lane >> 4;
  float* hbuf = (float*)(smem + 65536 + wave * 2176);  // [32][17] f32, per-wave

#pragma unroll
  for (int i = 0; i < 32; ++i) {
    int p = i * 256 + t;
    int row = p >> 6, c2 = p & 63;
    float w0 = W[row * 128 + c2 * 2];
    float w1 = W[row * 128 + c2 * 2 + 1];
    unsigned short h0, l0, h1, l1;
    bsplit(w0, h0, l0); bsplit(w1, h1, l1);
    int u32idx = row * 64 + ((((c2 * 4) ^ ((row & 7) << 4))) >> 2);
    ((unsigned*)Whi)[u32idx] = (unsigned)h0 | ((unsigned)h1 << 16);
    ((unsigned*)Wlo)[u32idx] = (unsigned)l0 | ((unsigned)l1 << 16);
  }
#pragma unroll
  for (int i = 0; i < 4; ++i) {
    int p = i * 256 + t;
    int row = p >> 6, c2 = p & 63;
    float w0 = Wo[row * 128 + c2 * 2];
    float w1 = Wo[row * 128 + c2 * 2 + 1];
    unsigned short h0, l0, h1, l1;
    bsplit(w0, h0, l0); bsplit(w1, h1, l1);
    int u32idx = row * 64 + ((((c2 * 4) ^ ((row & 7) << 4))) >> 2);
    ((unsigned*)WoHi)[u32idx] = (unsigned)h0 | ((unsigned)h1 << 16);
    ((unsigned*)WoLo)[u32idx] = (unsigned)l0 | ((unsigned)l1 << 16);
  }
  __syncthreads();

  short8v woh[4], wol[4];
  const int woswz = (s & 7) << 4;
#pragma unroll
  for (int ks = 0; ks < 4; ++ks) {
    int off = s * 256 + ((ks * 64 + q * 16) ^ woswz);
    woh[ks] = *(const short8v*)((char*)WoHi + off);
    wol[ks] = *(const short8v*)((char*)WoLo + off);
  }
  float bv[8];
#pragma unroll
  for (int nt = 0; nt < 8; ++nt) bv[nt] = B[nt * 16 + s];
  __syncthreads();  // Wo staging area now reusable as hbuf

  const int nchunks = (N + 127) >> 7;
  const int bswz = (s & 7) << 4;

  for (int chunk = blockIdx.x; chunk < nchunks; chunk += gridDim.x) {
    const int rowbase = chunk * 128 + wave * 32;

    short8v ahi[2][4], alo[2][4];
#pragma unroll
    for (int mt = 0; mt < 2; ++mt) {
      int row = rowbase + mt * 16 + s;
      int crow = row < N ? row : (N - 1);
      const float* xr = X + (size_t)crow * 128;
#pragma unroll
      for (int ks = 0; ks < 4; ++ks) {
        float4 f0 = *(const float4*)(xr + ks * 32 + q * 8);
        float4 f1 = *(const float4*)(xr + ks * 32 + q * 8 + 4);
        float v[8] = {f0.x, f0.y, f0.z, f0.w, f1.x, f1.y, f1.z, f1.w};
        frag_from8(v, ahi[mt][ks], alo[mt][ks]);
      }
    }

    float4v acc[2][8];
#pragma unroll
    for (int mt = 0; mt < 2; ++mt)
#pragma unroll
      for (int nt = 0; nt < 8; ++nt) acc[mt][nt] = (float4v){0.f, 0.f, 0.f, 0.f};

#pragma unroll
    for (int ks = 0; ks < 4; ++ks) {
      short8v bh[8];
#pragma unroll
      for (int nt = 0; nt < 8; ++nt) {
        int c = nt * 16 + s;
        int off = c * 256 + ((ks * 64 + q * 16) ^ bswz);
        bh[nt] = *(const short8v*)((char*)Whi + off);
      }
#pragma unroll
      for (int nt = 0; nt < 8; ++nt) {
#pragma unroll
        for (int mt = 0; mt < 2; ++mt) {
          acc[mt][nt] = __builtin_amdgcn_mfma_f32_16x16x32_bf16(ahi[mt][ks], bh[nt], acc[mt][nt], 0, 0, 0);
          acc[mt][nt] = __builtin_amdgcn_mfma_f32_16x16x32_bf16(alo[mt][ks], bh[nt], acc[mt][nt], 0, 0, 0);
        }
      }
#pragma unroll
      for (int nt = 0; nt < 8; ++nt) {
        int c = nt * 16 + s;
        int off = c * 256 + ((ks * 64 + q * 16) ^ bswz);
        short8v bl = *(const short8v*)((char*)Wlo + off);
#pragma unroll
        for (int mt = 0; mt < 2; ++mt)
          acc[mt][nt] = __builtin_amdgcn_mfma_f32_16x16x32_bf16(ahi[mt][ks], bl, acc[mt][nt], 0, 0, 0);
      }
    }

#pragma unroll
    for (int mt = 0; mt < 2; ++mt) {
      float4v gacc = (float4v){0.f, 0.f, 0.f, 0.f};
#pragma unroll
      for (int ks = 0; ks < 4; ++ks) {
#pragma unroll
        for (int j = 0; j < 2; ++j) {
          int nt = 2 * ks + j;
          int cl = j * 16 + s;
#pragma unroll
          for (int e = 0; e < 4; ++e)
            hbuf[cl * 17 + q * 4 + e] = fmaxf(acc[mt][nt][e] + bv[nt], 0.f);
        }
        float hv[8];
#pragma unroll
        for (int e = 0; e < 8; ++e) hv[e] = hbuf[(q * 8 + e) * 17 + s];
        short8v hh, hl;
        frag_from8(hv, hh, hl);
        gacc = __builtin_amdgcn_mfma_f32_16x16x32_bf16(hh, woh[ks], gacc, 0, 0, 0);
        gacc = __builtin_amdgcn_mfma_f32_16x16x32_bf16(hl, woh[ks], gacc, 0, 0, 0);
        gacc = __builtin_amdgcn_mfma_f32_16x16x32_bf16(hh, wol[ks], gacc, 0, 0, 0);
      }
      int grow = rowbase + mt * 16 + 4 * q;
#pragma unroll
      for (int e = 0; e < 4; ++e)
        if (grow + e < N) G[(size_t)(grow + e) * 16 + s] = gacc[e];
    }
  }
}

// ---------------- CSR build: combined histogram over 4 etypes -------------------------
// concat dst space: [0,NM)=rates, [NM,2NM)=dir, [2NM,2NM+NU)=rby, [2NM+NU,+ND)=dby
__global__ __launch_bounds__(256) void hist_kernel(
    const int* __restrict__ rd, const int* __restrict__ dd,
    const int* __restrict__ yd, const int* __restrict__ bd,
    int Er, int Edir, int Erby, int Edby, int NM, int NU,
    int* __restrict__ hist)
{
  int i = blockIdx.x * 256 + threadIdx.x;
  int c;
  if (i < Er) c = rd[i];
  else if (i < Er + Edir) c = NM + dd[i - Er];
  else if (i < Er + Edir + Erby) c = 2 * NM + yd[i - Er - Edir];
  else if (i < Er + Edir + Erby + Edby) c = 2 * NM + NU + bd[i - Er - Edir - Erby];
  else return;
  atomicAdd(&hist[c], 1);
}

// ---------------- 3-kernel exclusive scan over hist[H] -------------------------------
__global__ __launch_bounds__(256) void scan1_kernel(const int* __restrict__ hist,
                                                    int* __restrict__ bsum, int n)
{
  __shared__ int red[256];
  int i = blockIdx.x * 256 + threadIdx.x;
  red[threadIdx.x] = (i < n) ? hist[i] : 0;
  __syncthreads();
  for (int s = 128; s > 0; s >>= 1) {
    if (threadIdx.x < s) red[threadIdx.x] += red[threadIdx.x + s];
    __syncthreads();
  }
  if (threadIdx.x == 0) bsum[blockIdx.x] = red[0];
}

__global__ __launch_bounds__(1024) void scan2_kernel(int* __restrict__ bsum, int nB)
{
  __shared__ int tmp[1024];
  __shared__ int carry;
  if (threadIdx.x == 0) carry = 0;
  for (int base = 0; base < nB; base += 1024) {
    __syncthreads();
    int cl = carry;
    int i = base + threadIdx.x;
    int v = (i < nB) ? bsum[i] : 0;
    tmp[threadIdx.x] = v;
    __syncthreads();
    for (int d = 1; d < 1024; d <<= 1) {
      int add = (threadIdx.x >= (unsigned)d) ? tmp[threadIdx.x - d] : 0;
      __syncthreads();
      tmp[threadIdx.x] += add;
      __syncthreads();
    }
    int incl = tmp[threadIdx.x];
    if (i < nB) bsum[i] = incl - v + cl;
    __syncthreads();
    if (threadIdx.x == 1023) carry = cl + incl;
  }
}

__global__ __launch_bounds__(256) void scan3_kernel(
    const int* __restrict__ hist, const int* __restrict__ bsum,
    int* __restrict__ offs, int* __restrict__ cursor, int n)
{
  __shared__ int tmp[256];
  int i = blockIdx.x * 256 + threadIdx.x;
  int v = (i < n) ? hist[i] : 0;
  tmp[threadIdx.x] = v;
  __syncthreads();
  for (int d = 1; d < 256; d <<= 1) {
    int add = (threadIdx.x >= (unsigned)d) ? tmp[threadIdx.x - d] : 0;
    __syncthreads();
    tmp[threadIdx.x] += add;
    __syncthreads();
  }
  int excl = tmp[threadIdx.x] - v + bsum[blockIdx.x];
  if (i < n) { offs[i] = excl; cursor[i] = excl; }
}

// ---------------- XCD-partitioned ticket fill ----------------------------------------
// Each XCD group (blockIdx.x & 7, default round-robin block->XCD mapping) scans ALL
// edges but commits only buckets in its H/8 slice -> consecutive ssrc slots of a
// bucket are written by ONE XCD's L2 and aggregate into full-line writebacks.
// Correctness does not depend on the mapping (pure filter); only locality does.
__global__ __launch_bounds__(256) void ticket_xcd_kernel(
    const int* __restrict__ rs, const int* __restrict__ rd,
    const int* __restrict__ ds, const int* __restrict__ dd,
    const int* __restrict__ ys, const int* __restrict__ yd,
    const int* __restrict__ bs, const int* __restrict__ bd,
    int Er, int Edir, int Erby, int Edby, int NM, int NU, int H,
    int* __restrict__ cursor, int* __restrict__ sorted_src)
{
  const int xcd = blockIdx.x & 7;
  const int grp = blockIdx.x >> 3;
  const int ngrp = gridDim.x >> 3;
  const int lo = (int)(((long long)H * xcd) >> 3);
  const int hi = (int)(((long long)H * (xcd + 1)) >> 3);
  const int Etot = Er + Edir + Erby + Edby;

  for (int i = grp * 256 + threadIdx.x; i < Etot; i += ngrp * 256) {
    int c, s;
    if (i < Er) { s = rs[i]; c = rd[i]; }
    else if (i < Er + Edir) { int j = i - Er; s = ds[j]; c = NM + dd[j]; }
    else if (i < Er + Edir + Erby) { int j = i - Er - Edir; s = ys[j]; c = 2 * NM + yd[j]; }
    else { int j = i - Er - Edir - Erby; s = bs[j]; c = 2 * NM + NU + bd[j]; }
    if (c >= lo && c < hi) {
      int p = atomicAdd(&cursor[c], 1);
      sorted_src[p] = s;
    }
  }
}

// ---------------- pay[node] = ALPHA*g_self[node] + 0.5*mean_CSR(g_src) ----------------
__global__ __launch_bounds__(256) void gather_pay_kernel(
    const float* __restrict__ g_src, const float* __restrict__ g_self,
    const int* __restrict__ offs, const int* __restrict__ hist, int nb,
    const int* __restrict__ sorted_src, float* __restrict__ pay, int n)
{
  int tid = blockIdx.x * 256 + threadIdx.x;
  int node = tid >> 4, o = tid & 15;
  if (node >= n) return;
  int start = offs[nb + node], cnt = hist[nb + node];
  float sum = 0.f;
  for (int j = 0; j < cnt; ++j) {
    int s = sorted_src[start + j];
    sum += g_src[(size_t)s * 16 + o];
  }
  pay[(size_t)node * 16 + o] =
      ALPHA * g_self[(size_t)node * 16 + o] + 0.5f * sum / fmaxf((float)cnt, 1.f);
}

// ---------------- out[m] = b_out + a^2*g_m[m] + mean_rates(pay_u) + mean_dir(pay_d) ---
__global__ __launch_bounds__(256) void final_kernel(
    const float* __restrict__ gm, const float* __restrict__ pay_u,
    const float* __restrict__ pay_d,
    const int* __restrict__ offs, const int* __restrict__ hist,
    const int* __restrict__ sorted_src,
    const float* __restrict__ bo, float* __restrict__ out, int NM)
{
  int tid = blockIdx.x * 256 + threadIdx.x;
  int m = tid >> 4, o = tid & 15;
  if (m >= NM) return;
  int s0 = offs[m], c0 = hist[m];
  float sr = 0.f;
  for (int j = 0; j < c0; ++j) sr += pay_u[(size_t)sorted_src[s0 + j] * 16 + o];
  int s1 = offs[NM + m], c1 = hist[NM + m];
  float sd = 0.f;
  for (int j = 0; j < c1; ++j) sd += pay_d[(size_t)sorted_src[s1 + j] * 16 + o];
  out[(size_t)m * 16 + o] = bo[o] + ALPHA * ALPHA * gm[(size_t)m * 16 + o]
                          + sr / fmaxf((float)c0, 1.f) + sd / fmaxf((float)c1, 1.f);
}

extern "C" void kernel_launch(void* const* d_in, const int* in_sizes, int n_in,
                              void* d_out, int out_size, void* d_ws, size_t ws_size,
                              hipStream_t stream)
{
  const float* x_user  = (const float*)d_in[0];
  const float* x_movie = (const float*)d_in[1];
  const float* x_dir   = (const float*)d_in[2];
  const int* rates_src = (const int*)d_in[3];
  const int* rates_dst = (const int*)d_in[4];
  const int* rby_src   = (const int*)d_in[5];
  const int* rby_dst   = (const int*)d_in[6];
  const int* dir_src   = (const int*)d_in[7];
  const int* dir_dst   = (const int*)d_in[8];
  const int* dby_src   = (const int*)d_in[9];
  const int* dby_dst   = (const int*)d_in[10];
  const float* W_user  = (const float*)d_in[11];
  const float* b_user  = (const float*)d_in[12];
  const float* W_movie = (const float*)d_in[13];
  const float* b_movie = (const float*)d_in[14];
  const float* W_dir   = (const float*)d_in[15];
  const float* b_dir   = (const float*)d_in[16];
  const float* W_out   = (const float*)d_in[17];
  const float* b_out   = (const float*)d_in[18];

  const int NU = in_sizes[0] / 128, NM = in_sizes[1] / 128, ND = in_sizes[2] / 128;
  const int Er = in_sizes[3], Erby = in_sizes[5], Edir = in_sizes[7], Edby = in_sizes[9];
  const int Etot = Er + Edir + Erby + Edby;
  const int H = 2 * NM + NU + ND;                 // concat dst space
  const int nScanBlk = (H + 255) / 256;

  // ---- workspace layout
  char* w = (char*)d_ws;
  size_t off = 0;
  auto take = [&](size_t bytes) { char* p = w + off; off += (bytes + 255) & ~(size_t)255; return p; };
  float* g_u   = (float*)take((size_t)NU * 16 * 4);
  float* g_m   = (float*)take((size_t)NM * 16 * 4);
  float* g_d   = (float*)take((size_t)ND * 16 * 4);
  float* pay_u = (float*)take((size_t)NU * 16 * 4);
  float* pay_d = (float*)take((size_t)ND * 16 * 4);
  int* hist    = (int*)take((size_t)H * 4);        // zeroed
  int* offs    = (int*)take((size_t)H * 4);
  int* cursor  = (int*)take((size_t)H * 4);
  int* bsum    = (int*)take((size_t)nScanBlk * 4);
  int* ssrc    = (int*)take((size_t)Etot * 4);
  if (off > ws_size) return;

  // 1. zero histogram
  hipMemsetAsync(hist, 0, (size_t)H * 4, stream);

  // 2. combined histogram (also serves as degree arrays)
  hist_kernel<<<(Etot + 255) / 256, 256, 0, stream>>>(
      rates_dst, dir_dst, rby_dst, dby_dst, Er, Edir, Erby, Edby, NM, NU, hist);

  // 3. exclusive scan -> offs, cursor
  scan1_kernel<<<nScanBlk, 256, 0, stream>>>(hist, bsum, H);
  scan2_kernel<<<1, 1024, 0, stream>>>(bsum, nScanBlk);
  scan3_kernel<<<nScanBlk, 256, 0, stream>>>(hist, bsum, offs, cursor, H);

  // 4. XCD-partitioned ticket fill (8 groups x 256 blocks)
  ticket_xcd_kernel<<<2048, 256, 0, stream>>>(
      rates_src, rates_dst, dir_src, dir_dst, rby_src, rby_dst, dby_src, dby_dst,
      Er, Edir, Erby, Edby, NM, NU, H, cursor, ssrc);

  // 5. fused MFMA linear+relu+projection
  auto grid_for = [](int n) { int c = (n + 127) >> 7; return c < 512 ? c : 512; };
  fused_mfma_kernel<<<grid_for(NU), 256, 0, stream>>>(x_user,  W_user,  b_user,  W_out, g_u, NU);
  fused_mfma_kernel<<<grid_for(NM), 256, 0, stream>>>(x_movie, W_movie, b_movie, W_out, g_m, NM);
  fused_mfma_kernel<<<grid_for(ND), 256, 0, stream>>>(x_dir,   W_dir,   b_dir,   W_out, g_d, ND);

  // 6. pay_u = a*g_u + 0.5*mean_rby(g_m);  pay_d = a*g_d + 0.5*mean_dby(g_m)
  gather_pay_kernel<<<(NU * 16 + 255) / 256, 256, 0, stream>>>(
      g_m, g_u, offs, hist, 2 * NM, ssrc, pay_u, NU);
  gather_pay_kernel<<<(ND * 16 + 255) / 256, 256, 0, stream>>>(
      g_m, g_d, offs, hist, 2 * NM + NU, ssrc, pay_d, ND);

  // 7. out = b_out + a^2*g_m + mean_rates(pay_u) + mean_dir(pay_d)
  final_kernel<<<(NM * 16 + 255) / 256, 256, 0, stream>>>(
      g_m, pay_u, pay_d, offs, hist, ssrc, b_out, (float*)d_out, NM);
}